// Round 12
// baseline (2901.488 us; speedup 1.0000x reference)
//
#include <hip/hip_runtime.h>
#include <math.h>

// 512 rows of length 8192. Power iteration b <- normalize(b - T(x)C(c)b), 100x,
// then sigma = b.(b - TCb); out = mean(|sigma|).
//
// ROUND 22 KEY CHANGE: tail-barrier collapse + junction spectrum prefetch.
// r21 evidence: 2-blocks/CU is dispatcher-blocked for large-LDS 512t blocks
// (73,728 B + VGPR 108 + zero scratch -> occupancy still 23.6%); both
// cap-raising levers are dead (attributes ignored r11/r14; 1024t -> 64-cap
// spills r15). So optimize within 8 waves/CU:
//  1) Reduction needs ONE barrier, not three: P5 reads/writes only
//     thread-private buf slots (its own A-row; next-P1 rewrites the same
//     slots), so the only cross-thread datum in the tail is red[8].
//     7 -> 5 block barriers/iter.
//  2) Spectrum loads (G/S, L2/L3-resident) issued AT the junction multiply
//     behind wfence asm-memory clobbers -> compiler can't hoist -> ~600 cyc
//     L3 latency exposed twice/iter. Manual register prefetch at p2_mid
//     entry; B+C stages (~1000 cyc) cover it. Junction halves stay in a
//     rolled loop with STATIC branch selection (no runtime-indexed arrays).
//     CANARY: WRITE_SIZE must stay ~49 MB; GBs => prefetch blew the 128 cap.
//
// Radix-8 DIF math (verified r16-r21, absmax 0):
//   dft8: a[k]=y[k]+y[k+4]; b[k]=(y[k]-y[k+4])*W8^{Dk},
//         W8^{D}={1,(C2,D*C2),(0,D),(-C2,D*C2)}; dft4(a)->even, dft4(b)->odd.
//   Bin j lands at y[SIG[j]], SIG={0,4,1,5,2,6,3,7}; both directions store
//   slot j <- y[SIG[j]].
//
// LDS padding a(e) = e + (e>>4); padded affine offsets (carry-checked):
//   S1/A:    a = t+(t>>4) + 544k, mirror +4352
//   stage B: a = (t>>6)*544 + (t&63)+((t&63)>>4) + 68k
//   stage C: a = (t>>3)*68 + (t&7) + 8k + (k>>1)
//   mid:     a = 8t + (t>>1) + k
//   half1 of any stage: +4352 (= pad(e+4096)-pad(e)).
//
// Barrier topology: 4 phase barriers + 1 reduction barrier per iter.
// LDS per block: 69,632(buf) + 32(red) + 3,584(tB) + 448(tC) = 73,696 B.

#define NN 8192
#define NT 512
#define ROWS 512
#define BUFSZ 8704   // 8192 + 512 pad (float2)

__device__ __forceinline__ float2 cadd(float2 a, float2 b){ return make_float2(a.x+b.x, a.y+b.y); }
__device__ __forceinline__ float2 csub(float2 a, float2 b){ return make_float2(a.x-b.x, a.y-b.y); }
__device__ __forceinline__ float2 cmul(float2 a, float2 b){
  return make_float2(fmaf(a.x, b.x, -(a.y*b.y)), fmaf(a.x, b.y, a.y*b.x));
}
__device__ __forceinline__ float2 cscale(float2 a, float s){ return make_float2(a.x*s, a.y*s); }
__device__ __forceinline__ float2 conjf2(float2 a){ return make_float2(a.x, -a.y); }

// Wave-internal ordering fence (r19): no runtime cost; forbids reordering of
// LDS ops. Same-wave ds ops are processed in order by the LDS pipe. Also
// pins the manual prefetch loads upstream (loads can't sink across it).
__device__ __forceinline__ void wfence(){
  asm volatile("" ::: "memory");
  __builtin_amdgcn_sched_barrier(0);
}

static constexpr int SIG[8] = {0,4,1,5,2,6,3,7};   // bin j lives at y[SIG[j]]

template<int DIR> // DIR = -1 forward, +1 inverse
__device__ __forceinline__ void dft4(float2& a, float2& b, float2& c, float2& d){
  float2 t0=cadd(a,c), t1=csub(a,c), t2=cadd(b,d), t3=csub(b,d);
  float2 it3 = make_float2((float)(-DIR)*t3.y, (float)DIR*t3.x);
  a = cadd(t0,t2);
  c = csub(t0,t2);
  b = cadd(t1,it3);
  d = csub(t1,it3);
}

template<int DIR>
__device__ __forceinline__ void dft8i(float2 y[8]){
  const float C2 = 0.70710678119f;
  const float D  = (float)DIR;
  float2 a0=cadd(y[0],y[4]), a1=cadd(y[1],y[5]), a2=cadd(y[2],y[6]), a3=cadd(y[3],y[7]);
  float2 b0=csub(y[0],y[4]), b1=csub(y[1],y[5]), b2=csub(y[2],y[6]), b3=csub(y[3],y[7]);
  b1 = cmul(b1, make_float2(C2, D*C2));
  b2 = make_float2(-D*b2.y, D*b2.x);              // * (0, D)
  b3 = cmul(b3, make_float2(-C2, D*C2));
  dft4<DIR>(a0,a1,a2,a3);                          // even bins (natural)
  dft4<DIR>(b0,b1,b2,b3);                          // odd bins (natural)
  y[0]=a0; y[1]=a1; y[2]=a2; y[3]=a3;
  y[4]=b0; y[5]=b1; y[6]=b2; y[7]=b3;
}

// Padded offset within a stage: STEP*k (+ k>>1 for the st=8 stage).
template<int STEP, bool HK>
__device__ __forceinline__ constexpr int off8(int k){ return STEP*k + (HK ? (k>>1) : 0); }

// Forward radix-8 stage, chain twiddles (stage A + precompute).
template<int STEP, bool HK>
__device__ __forceinline__ void fwd_stage8(float2* buf, int a0, float2 w){
  float2 y[8];
  #pragma unroll
  for(int k=0;k<8;k++) y[k] = buf[a0 + off8<STEP,HK>(k)];
  dft8i<-1>(y);
  float2 tw = make_float2(1.f,0.f);
  #pragma unroll
  for(int j=0;j<8;j++){
    buf[a0 + off8<STEP,HK>(j)] = cmul(y[SIG[j]], tw);
    tw = cmul(tw, w);
  }
}

// Forward radix-8 stage, twiddles from LDS table twp[(j-1)*TS] = w^j (B/C).
template<int STEP, bool HK, int TS>
__device__ __forceinline__ void fwd_stage8_t(float2* buf, int a0, const float2* twp){
  float2 y[8];
  #pragma unroll
  for(int k=0;k<8;k++) y[k] = buf[a0 + off8<STEP,HK>(k)];
  dft8i<-1>(y);
  buf[a0] = y[SIG[0]];
  #pragma unroll
  for(int j=1;j<8;j++) buf[a0 + off8<STEP,HK>(j)] = cmul(y[SIG[j]], twp[(j-1)*TS]);
}

// Inverse radix-8 stage, conj(table) twiddles (B/C).
template<int STEP, bool HK, int TS>
__device__ __forceinline__ void inv_stage8_t(float2* buf, int a0, const float2* twp){
  float2 y[8];
  y[0] = buf[a0];
  #pragma unroll
  for(int k=1;k<8;k++) y[k] = cmul(buf[a0 + off8<STEP,HK>(k)], conjf2(twp[(k-1)*TS]));
  dft8i<1>(y);
  #pragma unroll
  for(int j=0;j<8;j++) buf[a0 + off8<STEP,HK>(j)] = y[SIG[j]];
}

// Last forward stage (precompute only): slot j <- bin j.
__device__ __forceinline__ void fwd_stage_last8(float2* buf, int aM){
  float2 y[8];
  #pragma unroll
  for(int k=0;k<8;k++) y[k] = buf[aM + k];
  dft8i<-1>(y);
  #pragma unroll
  for(int j=0;j<8;j++) buf[aM + j] = y[SIG[j]];
}

// Fused: fwd-last + complex-spectrum multiply (G from REGISTERS) + inv-first.
__device__ __forceinline__ void mid_junction_g8r(float2* buf, int aM, const float4 (&gp)[4]){
  float2 y[8];
  #pragma unroll
  for(int k=0;k<8;k++) y[k] = buf[aM + k];
  dft8i<-1>(y);
  float2 z[8];
  #pragma unroll
  for(int j2=0;j2<4;j2++){
    float4 g = gp[j2];
    z[2*j2]   = cmul(y[SIG[2*j2]],   make_float2(g.x, g.y));
    z[2*j2+1] = cmul(y[SIG[2*j2+1]], make_float2(g.z, g.w));
  }
  dft8i<1>(z);
  #pragma unroll
  for(int k=0;k<8;k++) buf[aM + k] = z[SIG[k]];
}

// Fused: fwd-last + real-spectrum multiply (REGISTERS) + inv-first.
__device__ __forceinline__ void mid_junction_s8r(float2* buf, int aM, const float4 (&sp)[2]){
  float2 y[8];
  #pragma unroll
  for(int k=0;k<8;k++) y[k] = buf[aM + k];
  dft8i<-1>(y);
  float2 z[8];
  float4 s0 = sp[0], s1 = sp[1];
  z[0] = cscale(y[SIG[0]], s0.x);
  z[1] = cscale(y[SIG[1]], s0.y);
  z[2] = cscale(y[SIG[2]], s0.z);
  z[3] = cscale(y[SIG[3]], s0.w);
  z[4] = cscale(y[SIG[4]], s1.x);
  z[5] = cscale(y[SIG[5]], s1.y);
  z[6] = cscale(y[SIG[6]], s1.z);
  z[7] = cscale(y[SIG[7]], s1.w);
  dft8i<1>(z);
  #pragma unroll
  for(int k=0;k<8;k++) buf[aM + k] = z[SIG[k]];
}

// ---- precompute-only S1 helpers (write LDS; barrier follows) ---------------

__device__ __forceinline__ void fwd_s1_real(float2* buf, int aS1, const float b[16], float2 w1){
  float2 tw = w1;
  const float2 step = make_float2(0.92387953251f, -0.38268343236f); // e^{-i pi/8}
  #pragma unroll
  for(int q=0;q<8;q++){
    int a = aS1 + 544*q;
    float d = b[q] - b[q+8];
    buf[a]        = make_float2(b[q] + b[q+8], 0.f);
    buf[a + 4352] = make_float2(d*tw.x, d*tw.y);
    tw = cmul(tw, step);
  }
}

__device__ __forceinline__ void fwd_s1_cplx(float2* buf, int aS1, const float2 in[16], float2 w1){
  float2 tw = w1;
  const float2 step = make_float2(0.92387953251f, -0.38268343236f);
  #pragma unroll
  for(int q=0;q<8;q++){
    int a = aS1 + 544*q;
    buf[a]        = cadd(in[q], in[q+8]);
    buf[a + 4352] = cmul(csub(in[q], in[q+8]), tw);
    tw = cmul(tw, step);
  }
}

// ---- in-loop fused phases (breg in VGPRs; w1/wA/ph in pinned regs) ---------

// P1: S1-fwd (from breg) + stage-A-fwd (chain twiddles), both halves.
__device__ __forceinline__ void p1_s1_a_fwd(float2* buf, const float breg[16],
                                            float2 w1, float2 wA, int aS1){
  float2 n[8], m[8];
  {
    float2 tw = w1;
    const float2 step = make_float2(0.92387953251f, -0.38268343236f);
    #pragma unroll
    for(int q=0;q<8;q++){
      float bq = breg[q], bq8 = breg[q+8];
      float d = bq - bq8;
      n[q] = make_float2(bq + bq8, 0.f);
      m[q] = make_float2(d*tw.x, d*tw.y);
      tw = cmul(tw, step);
    }
  }
  dft8i<-1>(n);
  { float2 tw = make_float2(1.f,0.f);
    #pragma unroll
    for(int j=0;j<8;j++){ buf[aS1 + 544*j] = cmul(n[SIG[j]], tw); tw = cmul(tw, wA); } }
  dft8i<-1>(m);
  { float2 tw = make_float2(1.f,0.f);
    #pragma unroll
    for(int j=0;j<8;j++){ buf[aS1 + 4352 + 544*j] = cmul(m[SIG[j]], tw); tw = cmul(tw, wA); } }
}

// P3: A-inv + inv-S1 + epilogue1 + phi-modulate + S1-fwd + A-fwd.
template<bool SIGMA>
__device__ __forceinline__ void p3_ainv_junc_afwd(float2* buf, float breg[16],
                                                  float2 w1, float2 wA, float2 ph0,
                                                  int aS1, float& loc, float sc1){
  float2 wAc = conjf2(wA);
  float2 y0[8], y1[8];
  { float2 tw = make_float2(1.f,0.f);
    #pragma unroll
    for(int k=0;k<8;k++){ y0[k] = cmul(buf[aS1 + 544*k], tw); tw = cmul(tw, wAc); } }
  dft8i<1>(y0);
  { float2 tw = make_float2(1.f,0.f);
    #pragma unroll
    for(int k=0;k<8;k++){ y1[k] = cmul(buf[aS1 + 4352 + 544*k], tw); tw = cmul(tw, wAc); } }
  dft8i<1>(y1);
  // time sample at slot q: half0 = y0[SIG[q]], half1 = y1[SIG[q]]
  float2 n[8], m[8];
  {
    float2 twf = w1;
    const float2 stepf = make_float2(0.92387953251f, -0.38268343236f);
    float2 ph = ph0;
    const float2 phstep = make_float2(0.98078528040f, -0.19509032202f);
    #pragma unroll
    for(int q=0;q<8;q++){
      float2 twi = conjf2(twf);          // bitwise == old conj-chain
      float2 z0 = y0[SIG[q]];
      float2 z1 = cmul(y1[SIG[q]], twi);
      float2 zn = cscale(cadd(z0,z1), sc1);
      float2 zm = cscale(csub(z0,z1), sc1);
      if (SIGMA) {
        loc += breg[q]*(breg[q]-zn.y) + breg[q+8]*(breg[q+8]-zm.y);
      } else {
        breg[q]   -= zn.y;
        breg[q+8] -= zm.y;
      }
      float2 vn = make_float2(zn.x*ph.x,  zn.x*ph.y);
      float2 vm = make_float2(zm.x*ph.y, -zm.x*ph.x);
      n[q] = cadd(vn, vm);
      m[q] = cmul(csub(vn, vm), twf);
      twf = cmul(twf, stepf); ph = cmul(ph, phstep);
    }
  }
  dft8i<-1>(n);
  { float2 tw = make_float2(1.f,0.f);
    #pragma unroll
    for(int j=0;j<8;j++){ buf[aS1 + 544*j] = cmul(n[SIG[j]], tw); tw = cmul(tw, wA); } }
  dft8i<-1>(m);
  { float2 tw = make_float2(1.f,0.f);
    #pragma unroll
    for(int j=0;j<8;j++){ buf[aS1 + 4352 + 544*j] = cmul(m[SIG[j]], tw); tw = cmul(tw, wA); } }
}

// P5: A-inv + inv-S1 + epilogue2 (updates breg, loc). Touches ONLY the
// calling thread's own buf slots (A-row) -> no barrier needed after it.
template<bool SIGMA>
__device__ __forceinline__ void p5_ainv_final(float2* buf, float breg[16],
                                              float2 w1, float2 wA, float2 ph0,
                                              int aS1, float& loc, float sc2){
  float2 wAc = conjf2(wA);
  float2 y0[8], y1[8];
  { float2 tw = make_float2(1.f,0.f);
    #pragma unroll
    for(int k=0;k<8;k++){ y0[k] = cmul(buf[aS1 + 544*k], tw); tw = cmul(tw, wAc); } }
  dft8i<1>(y0);
  { float2 tw = make_float2(1.f,0.f);
    #pragma unroll
    for(int k=0;k<8;k++){ y1[k] = cmul(buf[aS1 + 4352 + 544*k], tw); tw = cmul(tw, wAc); } }
  dft8i<1>(y1);
  {
    float2 twf = w1;
    const float2 stepf = make_float2(0.92387953251f, -0.38268343236f);
    float2 ph = ph0;
    const float2 phstep = make_float2(0.98078528040f, -0.19509032202f);
    #pragma unroll
    for(int q=0;q<8;q++){
      float2 twi = conjf2(twf);
      float2 z0 = y0[SIG[q]];
      float2 z1 = cmul(y1[SIG[q]], twi);
      float2 yn = cscale(cadd(z0,z1), sc2);
      float2 ym = cscale(csub(z0,z1), sc2);
      float qn = fmaf(ph.x, yn.x,  ph.y*yn.y);
      float qm = fmaf(ph.y, ym.x, -ph.x*ym.y);
      if (SIGMA) {
        loc -= breg[q]*qn + breg[q+8]*qm;
      } else {
        float bn = breg[q] - qn;
        breg[q] = bn; loc = fmaf(bn,bn,loc);
        bn = breg[q+8] - qm;
        breg[q+8] = bn; loc = fmaf(bn,bn,loc);
      }
      twf = cmul(twf, stepf); ph = cmul(ph, phstep);
    }
  }
}

// P2/P4: B -> C -> mid -> C-inv -> B-inv, wave-internal (fences, no barriers).
// Spectrum operands prefetched into registers at ENTRY: B+C (~1000 cyc) cover
// the L2/L3 latency that was previously exposed at the junction.
template<int MODE> // 1 = G junction (4 f4/half), 2 = S junction (2 f4/half)
__device__ __forceinline__ void p2_mid(float2* buf, const float2* tBt, const float2* tCt,
                                       int aB, int aC, int aM8,
                                       const float4* j0, const float4* j1){
  constexpr int NP = (MODE==1) ? 4 : 2;
  float4 p0[NP], p1[NP];
  #pragma unroll
  for(int i=0;i<NP;i++) p0[i] = j0[i];
  #pragma unroll
  for(int i=0;i<NP;i++) p1[i] = j1[i];
  #pragma clang loop unroll(disable)
  for(int h=0;h<2;++h) fwd_stage8_t<68,false,64>(buf, aB + 4352*h, tBt);
  wfence();
  #pragma clang loop unroll(disable)
  for(int h=0;h<2;++h) fwd_stage8_t<8,true,8>(buf, aC + 4352*h, tCt);
  wfence();
  #pragma clang loop unroll(disable)
  for(int h=0;h<2;++h){
    if (MODE==1){
      if (h==0) mid_junction_g8r(buf, aM8,        *(const float4(*)[4])&p0);
      else      mid_junction_g8r(buf, aM8 + 4352, *(const float4(*)[4])&p1);
    } else {
      if (h==0) mid_junction_s8r(buf, aM8,        *(const float4(*)[2])&p0);
      else      mid_junction_s8r(buf, aM8 + 4352, *(const float4(*)[2])&p1);
    }
  }
  wfence();
  #pragma clang loop unroll(disable)
  for(int h=0;h<2;++h) inv_stage8_t<8,true,8>(buf, aC + 4352*h, tCt);
  wfence();
  #pragma clang loop unroll(disable)
  for(int h=0;h<2;++h) inv_stage8_t<68,false,64>(buf, aB + 4352*h, tBt);
}

// One full iteration: 4 phase barriers + 1 reduction barrier (was 7).
template<bool SIGMA>
__device__ __forceinline__ float iterate(float2* buf, float* red, float breg[16],
                                         const float2* tBt, const float2* tCt,
                                         int t, int aS1, int aB, int aC, int aM8,
                                         float2 w1, float2 wA, float2 ph0,
                                         const float4* gx4, const float4* gc4,
                                         const float4* sb4){
  const float sc1 = 1.f/8192.f, sc2 = 1.f/8192.f;
  float loc = 0.f;

  p1_s1_a_fwd(buf, breg, w1, wA, aS1);
  __syncthreads();                                   // A out -> B in (cross-wave)
  p2_mid<1>(buf, tBt, tCt, aB, aC, aM8, gx4 + 4*t, gc4 + 4*t);
  __syncthreads();                                   // B-inv out -> A-inv in
  p3_ainv_junc_afwd<SIGMA>(buf, breg, w1, wA, ph0, aS1, loc, sc1);
  __syncthreads();
  p2_mid<2>(buf, tBt, tCt, aB, aC, aM8, sb4 + 2*t, sb4 + 1024 + 2*t);
  __syncthreads();
  p5_ainv_final<SIGMA>(buf, breg, w1, wA, ph0, aS1, loc, sc2);

  // Reduction: P5 touched only thread-private buf slots, and next-P1 rewrites
  // exactly those slots -> the ONLY cross-thread datum here is red[8].
  #pragma unroll
  for(int off=32; off; off>>=1) loc += __shfl_down(loc, off, 64);
  if((t&63)==0) red[t>>6] = loc;
  __syncthreads();                                   // publish red
  float tot = 0.f;
  #pragma unroll
  for(int w=0;w<8;w++) tot += red[w];
  // No trailing barrier: red is next written only after 4 more barriers.
  return tot;
}

__global__ void msvl_zero(float* out){ out[0] = 0.f; }

__global__ void __launch_bounds__(512)
msvl_main(float* x, float* circ, float* b0, float* out){
  __shared__ float2 buf[BUFSZ];        // 69,632 B
  __shared__ float red[8];
  __shared__ float2 tB[7*64];          //  3,584 B  wB^j per (t&63)
  __shared__ float2 tC[7*8];           //    448 B  wC^j per (t&7)
  // total 73,696 B
  const int t = threadIdx.x;
  const int row = blockIdx.x;

  float* xrow = x    + (size_t)row * NN;
  float* crow = circ + (size_t)row * NN;
  float* brow = b0   + (size_t)row * NN;

  // Padded per-thread bases (iteration-invariant).
  const int aS1 = t + (t>>4);                              // S1 / stage-A base
  const int aB  = (t>>6)*544 + (t&63) + ((t&63)>>4);       // stage B
  const int aC  = (t>>3)*68 + (t&7);                       // stage C
  const int aM8 = 8*t + (t>>1);                            // mid blocks

  // Twiddle scalars; B/C power tables filled once (bitwise-identical chains).
  float s1v,c1v,sAv,cAv,sBv,cBv,sCv,cCv,psv,pcv;
  __sincosf(-6.28318530718f*(float)t/8192.f,       &s1v,&c1v);   // w1 (S1)
  __sincosf(-6.28318530718f*(float)t/4096.f,       &sAv,&cAv);   // wA (st=512)
  __sincosf(-6.28318530718f*(float)(t&63)/512.f,   &sBv,&cBv);   // wB (st=64)
  __sincosf(-6.28318530718f*(float)(t&7)/64.f,     &sCv,&cCv);   // wC (st=8)
  __sincosf(-3.14159265359f*(float)t/8192.f,       &psv,&pcv);   // phi
  const float2 phstep = make_float2(0.98078528040f, -0.19509032202f);
  if (t < 64) {
    float2 w = make_float2(cBv,sBv), tw = w;
    #pragma unroll
    for(int j=1;j<8;j++){ tB[(j-1)*64 + t] = tw; tw = cmul(tw, w); }
  }
  if (t < 8) {
    float2 w = make_float2(cCv,sCv), tw = w;
    #pragma unroll
    for(int j=1;j<8;j++){ tC[(j-1)*8 + t] = tw; tw = cmul(tw, w); }
  }

  const float2* tBt = tB + (t&63);
  const float2* tCt = tC + (t&7);

  float breg[16];

  // --- init: b = b0 / ||b0||  (barriers here also publish the tables) ------
  {
    float nrm = 0.f;
    #pragma unroll
    for(int j=0;j<16;j++){ float v = brow[t+512*j]; breg[j]=v; nrm = fmaf(v,v,nrm); }
    #pragma unroll
    for(int off=32; off; off>>=1) nrm += __shfl_down(nrm, off, 64);
    if((t&63)==0) red[t>>6] = nrm;
    __syncthreads();
    float tot = 0.f;
    #pragma unroll
    for(int w=0;w<8;w++) tot += red[w];
    float isc = rsqrtf(tot);
    #pragma unroll
    for(int j=0;j<16;j++) breg[j] *= isc;
    __syncthreads();
  }

  // --- precompute spectra (3 forward FFTs) -> global ------------------------
  // G: gx[8t+j] (xrow), gc[8t+j] (crow);  S2o: brow[8t+j], brow[4096+8t+j].
  {
    const float2 w1 = make_float2(c1v,s1v), wA = make_float2(cAv,sAv);
    float fj[16], dj[16];
    #pragma unroll
    for(int j=0;j<16;j++){
      int n = t + 512*j;
      float xn = xrow[n];
      float xr = (n==0) ? 0.f : xrow[NN - n];
      fj[j] = xn + xr;
      dj[j] = xn - xr;
    }
    // FFT(f) -> 0.5*S2e (register se[16])
    fwd_s1_real(buf, aS1, fj, w1);
    __syncthreads();
    #pragma clang loop unroll(disable)
    for(int h=0; h<2; ++h) fwd_stage8<544,false>(buf, aS1 + 4352*h, wA);
    __syncthreads();
    #pragma clang loop unroll(disable)
    for(int h=0; h<2; ++h) fwd_stage8_t<68,false,64>(buf, aB + 4352*h, tBt);
    __syncthreads();
    #pragma clang loop unroll(disable)
    for(int h=0; h<2; ++h) fwd_stage8_t<8,true,8>(buf, aC + 4352*h, tCt);
    __syncthreads();
    #pragma clang loop unroll(disable)
    for(int h=0; h<2; ++h) fwd_stage_last8(buf, aM8 + 4352*h);
    __syncthreads();
    float se[16];
    #pragma unroll
    for(int j=0;j<8;j++){ se[j] = 0.5f * buf[aM8 + j].x; se[8+j] = 0.5f * buf[aM8 + 4352 + j].x; }
    __syncthreads();
    // FFT(d*phi) -> 0.5*S2o -> brow
    {
      float2 ph = make_float2(pcv, psv);
      float2 tmp[16];
      #pragma unroll
      for(int j=0;j<16;j++){ tmp[j] = make_float2(dj[j]*ph.x, dj[j]*ph.y); ph = cmul(ph, phstep); }
      fwd_s1_cplx(buf, aS1, tmp, w1);
    }
    __syncthreads();
    #pragma clang loop unroll(disable)
    for(int h=0; h<2; ++h) fwd_stage8<544,false>(buf, aS1 + 4352*h, wA);
    __syncthreads();
    #pragma clang loop unroll(disable)
    for(int h=0; h<2; ++h) fwd_stage8_t<68,false,64>(buf, aB + 4352*h, tBt);
    __syncthreads();
    #pragma clang loop unroll(disable)
    for(int h=0; h<2; ++h) fwd_stage8_t<8,true,8>(buf, aC + 4352*h, tCt);
    __syncthreads();
    #pragma clang loop unroll(disable)
    for(int h=0; h<2; ++h) fwd_stage_last8(buf, aM8 + 4352*h);
    __syncthreads();
    #pragma unroll
    for(int j=0;j<8;j++){
      brow[8*t + j]        = 0.5f * buf[aM8 + j].x;
      brow[4096 + 8*t + j] = 0.5f * buf[aM8 + 4352 + j].x;
    }
    __syncthreads();
    // FFT(c) -> Fc; G = Fc*(1 + i*se) -> gx (xrow) / gc (crow)
    #pragma unroll
    for(int j=0;j<16;j++) fj[j] = crow[t+512*j];
    fwd_s1_real(buf, aS1, fj, w1);
    __syncthreads();
    #pragma clang loop unroll(disable)
    for(int h=0; h<2; ++h) fwd_stage8<544,false>(buf, aS1 + 4352*h, wA);
    __syncthreads();
    #pragma clang loop unroll(disable)
    for(int h=0; h<2; ++h) fwd_stage8_t<68,false,64>(buf, aB + 4352*h, tBt);
    __syncthreads();
    #pragma clang loop unroll(disable)
    for(int h=0; h<2; ++h) fwd_stage8_t<8,true,8>(buf, aC + 4352*h, tCt);
    __syncthreads();
    #pragma clang loop unroll(disable)
    for(int h=0; h<2; ++h) fwd_stage_last8(buf, aM8 + 4352*h);
    __syncthreads();
    {
      float2* gx = (float2*)xrow;
      float2* gc = (float2*)crow;
      #pragma unroll
      for(int j=0;j<8;j++){
        float2 f0 = buf[aM8 + j];
        float2 f1 = buf[aM8 + 4352 + j];
        gx[8*t + j] = make_float2(fmaf(-f0.y, se[j],   f0.x), fmaf(f0.x, se[j],   f0.y));
        gc[8*t + j] = make_float2(fmaf(-f1.y, se[8+j], f1.x), fmaf(f1.x, se[8+j], f1.y));
      }
    }
    __syncthreads();
  }

  const float4* gx4 = (const float4*)xrow;
  const float4* gc4 = (const float4*)crow;
  const float4* sb4 = (const float4*)brow;

  // --- 100 power iterations (rolled) ----------------------------------------
  #pragma clang loop unroll(disable)
  for(int iter=0; iter<100; ++iter){
    // Pin the 6 persistent twiddle scalars (blocks LICM of derived chains)
    // + memory clobber (blocks hoisting of the loop-invariant G/S loads).
    asm volatile("" : "+v"(c1v), "+v"(s1v), "+v"(cAv), "+v"(sAv),
                      "+v"(pcv), "+v"(psv));
    asm volatile("" ::: "memory");
    const float2 w1 = make_float2(c1v,s1v), wA = make_float2(cAv,sAv),
                 ph0 = make_float2(pcv,psv);
    float tot = iterate<false>(buf, red, breg, tBt, tCt,
                               t, aS1, aB, aC, aM8, w1, wA, ph0, gx4, gc4, sb4);
    float s = rsqrtf(tot);
    #pragma unroll
    for(int j=0;j<16;j++) breg[j] *= s;
  }

  // --- final matvec for sigma ------------------------------------------------
  {
    asm volatile("" : "+v"(c1v), "+v"(s1v), "+v"(cAv), "+v"(sAv),
                      "+v"(pcv), "+v"(psv));
    asm volatile("" ::: "memory");
    const float2 w1 = make_float2(c1v,s1v), wA = make_float2(cAv,sAv),
                 ph0 = make_float2(pcv,psv);
    float tot = iterate<true>(buf, red, breg, tBt, tCt,
                              t, aS1, aB, aC, aM8, w1, wA, ph0, gx4, gc4, sb4);
    if(t == 0) atomicAdd(out, fabsf(tot) * (1.f/512.f));
  }
}

extern "C" void kernel_launch(void* const* d_in, const int* in_sizes, int n_in,
                              void* d_out, int out_size, void* d_ws, size_t ws_size,
                              hipStream_t stream) {
  float* x    = (float*)d_in[0];
  float* circ = (float*)d_in[1];
  float* b0   = (float*)d_in[2];
  float* out  = (float*)d_out;

  hipLaunchKernelGGL(msvl_zero, dim3(1), dim3(1), 0, stream, out);
  hipLaunchKernelGGL(msvl_main, dim3(ROWS), dim3(NT), 0, stream,
                     x, circ, b0, out);
}